// Round 7
// baseline (107.956 us; speedup 1.0000x reference)
//
#include <hip/hip_runtime.h>

// HTMM: B_TREES=8, ARITY=4, DEPTH=8, C=8, M=100, NGEN=4
constexpr int OFFS1 = 8, OFFS2 = 40, OFFS3 = 168, OFFS4 = 680;
constexpr int OFFS5 = 2728, OFFS6 = 10920, OFFS7 = 43688, OFFS8 = 174760;

// lane mapping within a 32-lane group: r = g*8+s (g = gen, s = state)
// wtd_l[(j*8+d)*32 + g*8+s] = P(child=s | parent=d, pos j, gen g)
// emt_h[m*32 + g*8+c] (fp16); etab_h[(m*4+j)*32 + g*8+d] = sum_c P(c|d,j,g)em(m|c,g) (fp16)

#define WB() __builtin_amdgcn_wave_barrier()
#define AG_ST(p, v) __hip_atomic_store((p), (v), __ATOMIC_RELAXED, __HIP_MEMORY_SCOPE_AGENT)
#define AG_LD(p) __hip_atomic_load((p), __ATOMIC_RELAXED, __HIP_MEMORY_SCOPE_AGENT)

template <int CTRL>
static __device__ __forceinline__ float dppmov(float v) {
  return __int_as_float(__builtin_amdgcn_update_dpp(0, __float_as_int(v), CTRL, 0xF, 0xF, true));
}
// octet sum, all 8 lanes, pure VALU: quad xor1 + xor2 + row_half_mirror (s <-> 7-s, opposite quad)
static __device__ __forceinline__ float bfly8(float v) {
  v += dppmov<0xB1>(v);   // quad_perm [1,0,3,2]
  v += dppmov<0x4E>(v);   // quad_perm [2,3,0,1]
  v += dppmov<0x141>(v);  // row_half_mirror
  return v;
}
// 16-lane row sum (emission softmax partitions)
static __device__ __forceinline__ float red16(float v) {
  v += dppmov<0xB1>(v);
  v += dppmov<0x4E>(v);
  v += dppmov<0x141>(v);
  v += dppmov<0x140>(v);  // row_mirror
  return v;
}
// all-gather of an octet-distributed value: a[i] = v[s ^ PX[i]]
constexpr int PX[8] = {0, 1, 2, 3, 7, 6, 5, 4};
struct O8 { float a[8]; };
static __device__ __forceinline__ O8 gather8(float v) {
  O8 o;
  o.a[0] = v;
  o.a[1] = dppmov<0xB1>(v);   // v[s^1]
  o.a[2] = dppmov<0x4E>(v);   // v[s^2]
  o.a[3] = dppmov<0x1B>(v);   // quad_perm [3,2,1,0] -> v[s^3]
  o.a[4] = dppmov<0x141>(v);        // v[7-s]   = v[s^7]
  o.a[5] = dppmov<0x141>(o.a[1]);   // v[s^6]
  o.a[6] = dppmov<0x141>(o.a[2]);   // v[s^5]
  o.a[7] = dppmov<0x141>(o.a[3]);   // v[s^4]
  return o;
}
static __device__ __forceinline__ float mvc(const float w[8], const O8& o) {
  float acc = 0.f;
#pragma unroll
  for (int i = 0; i < 8; i++) acc += w[i] * o.a[i];
  return acc;
}
static __device__ __forceinline__ float mv_sel(const float wq[4][8], const O8& o, int j) {
  float acc = 0.f;
#pragma unroll
  for (int i = 0; i < 8; i++) {
    float w01 = (j & 1) ? wq[1][i] : wq[0][i];
    float w23 = (j & 1) ? wq[3][i] : wq[2][i];
    float w = (j & 2) ? w23 : w01;
    acc += w * o.a[i];
  }
  return acc;
}
static __device__ __forceinline__ float dot8r(const float w[8], const float* p) {
  const float4* q = (const float4*)p;
  float4 a = q[0], b = q[1];
  return w[0] * a.x + w[1] * a.y + w[2] * a.z + w[3] * a.w +
         w[4] * b.x + w[5] * b.y + w[6] * b.z + w[7] * b.w;
}
static __device__ __forceinline__ void ld8(const float* p, float pv[8]) {
  const float4* q = (const float4*)p;
  float4 a = q[0], b = q[1];
  pv[0] = a.x; pv[1] = a.y; pv[2] = a.z; pv[3] = a.w;
  pv[4] = b.x; pv[5] = b.y; pv[6] = b.z; pv[7] = b.w;
}
static __device__ __forceinline__ float rcpf(float x) { return __builtin_amdgcn_rcpf(x); }

// LDS carve (floats):
// [0,1024) wtd_l | [1024,1056) pit_l | [1056,3104) stash 16x4x32
// [3104,3616) rat5buf 16x32 | [3616,3744) pri4buf 4x32
// [3744,11936) big: emt_f32 (phase0, 3200) / rat4_l (phase2, 8192)
// [11936,13536) emt_h (3200 halves) | [13536,19936) etab_h (12800 halves)
constexpr int SMEM_F = 19936;

// Single fused kernel: 512 blocks x 512 threads. 16 groups/block, one level-5
// subtree each (levels 5..8 + L4 in-block); last block per tree (64) does 3..0.
__global__ __launch_bounds__(512) void k_all(const int* __restrict__ x,
                                             const float* __restrict__ A,
                                             const float* __restrict__ Bm,
                                             const float* __restrict__ Pi,
                                             float* __restrict__ RAT4,
                                             float* __restrict__ blocksum,
                                             unsigned* __restrict__ ctr,
                                             float* __restrict__ out) {
  __shared__ __align__(16) float smem[SMEM_F];
  __shared__ float llb[4];
  __shared__ int lastf;
  float* wtd_l = smem;
  float* pit_l = smem + 1024;
  float* stash = smem + 1056;
  float* rat5buf = smem + 3104;
  float* pri4buf = smem + 3616;
  float* emt_f = smem + 3744;   // phase-0 only
  float* rat4_l = smem + 3744;  // phase-2 only (aliased)
  _Float16* emt_h = (_Float16*)(smem + 11936);
  _Float16* etab_h = (_Float16*)(smem + 13536);

  int t = threadIdx.x;
  int r = t & 31, g = r >> 3, s = r & 7, grp = t >> 5;
  int b = blockIdx.x, tree = b >> 6;  // 64 blocks per tree

  // ---------------- phase 0: tables ----------------
  if (t < 128) {  // A softmax over child state; thread owns column (d,j,gg)
    int d = t >> 4, j = (t >> 2) & 3, gg = t & 3;
    float v[8], sum = 0.f;
#pragma unroll
    for (int ss = 0; ss < 8; ss++) { v[ss] = __expf(A[((ss * 8 + d) * 4 + j) * 4 + gg]); sum += v[ss]; }
    float inv = rcpf(sum);
#pragma unroll
    for (int ss = 0; ss < 8; ss++) wtd_l[(j * 8 + d) * 32 + gg * 8 + ss] = v[ss] * inv;
  }
  if (t < 4) {  // Pi softmax
    float v[8], sum = 0.f;
#pragma unroll
    for (int c = 0; c < 8; c++) { v[c] = __expf(Pi[c * 4 + t]); sum += v[c]; }
    float inv = rcpf(sum);
#pragma unroll
    for (int c = 0; c < 8; c++) pit_l[t * 8 + c] = v[c] * inv;
    llb[t] = 0.f;
  }
  {  // emission softmax over m: 32 rows (c,gg) x 16 partitions, red16 reduce
    int row = t >> 4, part = t & 15, c = row >> 2, gg = row & 3;
    int m0 = part < 4 ? part * 7 : 28 + (part - 4) * 6;
    int mn = part < 4 ? 7 : 6;
    float sum = 0.f;
    for (int m = m0; m < m0 + mn; m++) sum += __expf(Bm[(c * 100 + m) * 4 + gg]);
    sum = red16(sum);
    float inv = rcpf(sum);
    for (int m = m0; m < m0 + mn; m++) {
      float e = __expf(Bm[(c * 100 + m) * 4 + gg]) * inv;
      emt_f[m * 32 + gg * 8 + c] = e;
      emt_h[m * 32 + gg * 8 + c] = (_Float16)e;
    }
  }
  __syncthreads();
  {  // Etab via gather8: group handles j = grp&3, m-quarter = grp>>2
    int j = grp & 3, mq = grp >> 2;
    float wu8[8];
#pragma unroll
    for (int i = 0; i < 8; i++) wu8[i] = wtd_l[(j * 8 + s) * 32 + g * 8 + (s ^ PX[i])];
    for (int m = mq * 25; m < mq * 25 + 25; m++) {
      O8 o = gather8(emt_f[m * 32 + r]);
      etab_h[(m * 4 + j) * 32 + r] = (_Float16)mvc(wu8, o);
    }
  }
  // per-lane permuted transition weights (stable wtd_l)
  float wq[4][8], wup_r[4][8];
#pragma unroll
  for (int j = 0; j < 4; j++) {
#pragma unroll
    for (int i = 0; i < 8; i++) wq[j][i] = wtd_l[(j * 8 + (s ^ PX[i])) * 32 + r];
    ld8(&wtd_l[(j * 8 + s) * 32 + g * 8], wup_r[j]);  // row P(child=c | parent=s, j, g)
  }
  __syncthreads();

  // ---------------- phase 1: one level-5 subtree per group ----------------
  float* st = stash + grp * 128;
  int n5 = b * 16 + grp;
  float acc = 0.f;

  // path walk root -> level-5 (all DPP, no LDS); capture level-4 prior
  float v = pit_l[r], pri4 = 0.f;
#pragma unroll
  for (int k = 1; k <= 5; k++) {
    O8 o = gather8(v);
    int j = (n5 >> (2 * (5 - k))) & 3;
    v = mv_sel(wq, o, j);
    if (k == 4) pri4 = v;
  }
  float v5 = v;
  O8 o5 = gather8(v5);

  const int4* x8v = (const int4*)(x + OFFS8 + n5 * 64);
  const int4* x7v = (const int4*)(x + OFFS7 + n5 * 16);
  int4 x6v = *(const int4*)(x + OFFS6 + n5 * 4);
  int x5s = x[OFFS5 + n5];
  const int* x6a = (const int*)&x6v;

  float l6r[4];
#pragma unroll
  for (int q6 = 0; q6 < 4; q6++) {
    int4 x7 = x7v[q6];
    const int* x7a = (const int*)&x7;
    float u6 = mvc(wq[q6], o5);
    O8 o6 = gather8(u6);
    // prefetch 16 leaf-operator values (independent u16 LDS loads)
    float Ep[4][4];
#pragma unroll
    for (int q7 = 0; q7 < 4; q7++) {
      int4 xl = x8v[q6 * 4 + q7];
      const int* xla = (const int*)&xl;
#pragma unroll
      for (int j = 0; j < 4; j++) Ep[q7][j] = (float)etab_h[(xla[j] * 4 + j) * 32 + r];
    }
#pragma unroll
    for (int q7 = 0; q7 < 4; q7++) {
      float u7 = mvc(wq[q7], o6);
      float n0 = bfly8(u7 * Ep[q7][0]);
      float n1 = bfly8(u7 * Ep[q7][1]);
      float n2 = bfly8(u7 * Ep[q7][2]);
      float n3 = bfly8(u7 * Ep[q7][3]);
      float p01 = n0 * n1, p23 = n2 * n3;  // pairwise: safe vs underflow
      float prod = (Ep[q7][0] * Ep[q7][1] * rcpf(p01)) * (Ep[q7][2] * Ep[q7][3] * rcpf(p23));
      acc += __logf(p01) + __logf(p23);
      float em = (float)emt_h[x7a[q7] * 32 + r];
      float nu7 = bfly8(u7 * em * prod);
      acc += __logf(nu7);
      st[q7 * 32 + r] = em * prod * rcpf(nu7);
    }
    WB();
    float prod6 = 1.f;
#pragma unroll
    for (int j = 0; j < 4; j++) prod6 *= dot8r(wup_r[j], st + j * 32 + g * 8);
    WB();
    float em6 = (float)emt_h[x6a[q6] * 32 + r];
    float nu6 = bfly8(u6 * em6 * prod6);
    acc += __logf(nu6);
    l6r[q6] = em6 * prod6 * rcpf(nu6);
  }
  // level-5 upward
#pragma unroll
  for (int j = 0; j < 4; j++) st[j * 32 + r] = l6r[j];
  WB();
  {
    float prod5 = 1.f;
#pragma unroll
    for (int j = 0; j < 4; j++) prod5 *= dot8r(wup_r[j], st + j * 32 + g * 8);
    float em5 = (float)emt_h[x5s * 32 + r];
    float nu5 = bfly8(v5 * em5 * prod5);
    acc += __logf(nu5);
    rat5buf[grp * 32 + r] = em5 * prod5 * rcpf(nu5);
  }
  if ((grp & 3) == 0) pri4buf[(grp >> 2) * 32 + r] = pri4;
  __syncthreads();

  // level-4: 4 nodes per block (groups 0-3)
  if (grp < 4) {
    int n4 = b * 4 + grp;
    float prod = 1.f;
#pragma unroll
    for (int j = 0; j < 4; j++) prod *= dot8r(wup_r[j], &rat5buf[(grp * 4 + j) * 32 + g * 8]);
    float em = (float)emt_h[x[OFFS4 + n4] * 32 + r];
    float nu = bfly8(pri4buf[grp * 32 + r] * em * prod);
    acc += __logf(nu);
    AG_ST(&RAT4[n4 * 32 + r], em * prod * rcpf(nu));
  }

  if (s == 0) atomicAdd(&llb[g], acc);
  __syncthreads();
  if (t < 4) AG_ST(&blocksum[b * 4 + t], llb[t]);
  asm volatile("s_waitcnt vmcnt(0)" ::: "memory");  // RAT4+blocksum at coherent point
  __syncthreads();
  if (t == 0) {
    unsigned old = __hip_atomic_fetch_add(&ctr[tree * 32], 1u, __ATOMIC_RELAXED,
                                          __HIP_MEMORY_SCOPE_AGENT);
    lastf = (old == 63u || old == 0xAAAAAAE9u) ? 1 : 0;  // zero-init or 0xAA-poison
  }
  __syncthreads();
  if (!lastf) return;

  // ---------------- phase 2: last block of the tree does levels 3..0 ----------------
  if (t < 4) llb[t] = 0.f;
  {  // stage tree's RAT4 slice (8192 floats) with batched agent loads
    float tmp[16];
#pragma unroll
    for (int i = 0; i < 16; i++) tmp[i] = AG_LD(&RAT4[tree * 8192 + i * 512 + t]);
#pragma unroll
    for (int i = 0; i < 16; i++) rat4_l[i * 512 + t] = tmp[i];
  }
  __syncthreads();

  float acc2 = 0.f;
  {  // 16 groups = 16 L2 subtrees
    int n2g = tree * 16 + grp;
    float v2 = pit_l[r];
#pragma unroll
    for (int k = 1; k <= 2; k++) {
      O8 o = gather8(v2);
      int j = (n2g >> (2 * (2 - k))) & 3;
      v2 = mv_sel(wq, o, j);
    }
    O8 o2 = gather8(v2);
#pragma unroll
    for (int j3 = 0; j3 < 4; j3++) {
      int n3g = n2g * 4 + j3;
      int i3l = grp * 4 + j3;
      float p3 = mvc(wq[j3], o2);
      float prod = 1.f;
#pragma unroll
      for (int j = 0; j < 4; j++) prod *= dot8r(wup_r[j], &rat4_l[(i3l * 4 + j) * 32 + g * 8]);
      float em = (float)emt_h[x[OFFS3 + n3g] * 32 + r];
      float nu = bfly8(p3 * em * prod);
      acc2 += __logf(nu);
      st[j3 * 32 + r] = em * prod * rcpf(nu);
    }
    WB();
    float prod = 1.f;
#pragma unroll
    for (int j = 0; j < 4; j++) prod *= dot8r(wup_r[j], st + j * 32 + g * 8);
    WB();
    float em = (float)emt_h[x[OFFS2 + n2g] * 32 + r];
    float nu = bfly8(v2 * em * prod);
    acc2 += __logf(nu);
    rat5buf[grp * 32 + r] = em * prod * rcpf(nu);  // rat2
  }
  __syncthreads();
  if (grp < 4) {  // level 1
    int n1g = tree * 4 + grp;
    O8 op = gather8(pit_l[r]);
    float v1 = mv_sel(wq, op, grp);
    float prod = 1.f;
#pragma unroll
    for (int j = 0; j < 4; j++) prod *= dot8r(wup_r[j], &rat5buf[(grp * 4 + j) * 32 + g * 8]);
    float em = (float)emt_h[x[OFFS1 + n1g] * 32 + r];
    float nu = bfly8(v1 * em * prod);
    acc2 += __logf(nu);
    pri4buf[grp * 32 + r] = em * prod * rcpf(nu);  // rat1
  }
  __syncthreads();
  if (grp == 0) {  // root
    float prod = 1.f;
#pragma unroll
    for (int j = 0; j < 4; j++) prod *= dot8r(wup_r[j], &pri4buf[j * 32 + g * 8]);
    float em = (float)emt_h[x[tree] * 32 + r];
    float nu = bfly8(pit_l[r] * em * prod);
    acc2 += __logf(nu);
  }
  if (s == 0) atomicAdd(&llb[g], acc2);
  __syncthreads();
  // reduce this tree's 64 blocks x 4 gens (256 values; gen preserved mod 4)
  float* red = rat4_l;
  if (t < 256) red[t] = AG_LD(&blocksum[tree * 256 + t]);
  __syncthreads();
#pragma unroll
  for (int off = 128; off >= 4; off >>= 1) {
    if (t < off) red[t] += red[t + off];
    __syncthreads();
  }
  if (t < 4) out[tree * 4 + t] = red[t] + llb[t];
}

extern "C" void kernel_launch(void* const* d_in, const int* in_sizes, int n_in,
                              void* d_out, int out_size, void* d_ws, size_t ws_size,
                              hipStream_t stream) {
  const int* x = (const int*)d_in[0];
  const float* A = (const float*)d_in[1];
  const float* Bm = (const float*)d_in[2];
  const float* Pi = (const float*)d_in[3];
  float* ws = (float*)d_ws;
  unsigned* ctr = (unsigned*)d_ws;   // 8 trees x stride-32 uints (poison-based count)
  float* blocksum = ws + 256;        // 512 blocks x 4
  float* RAT4 = ws + 256 + 2048;     // 2048*32
  float* out = (float*)d_out;

  k_all<<<512, 512, 0, stream>>>(x, A, Bm, Pi, RAT4, blocksum, ctr, out);
}

// Round 8
// 98.146 us; speedup vs baseline: 1.1000x; 1.1000x over previous
//
#include <hip/hip_runtime.h>

// HTMM: B_TREES=8, ARITY=4, DEPTH=8, C=8, M=100, NGEN=4
constexpr int OFFS1 = 8, OFFS2 = 40, OFFS3 = 168, OFFS4 = 680;
constexpr int OFFS5 = 2728, OFFS6 = 10920, OFFS7 = 43688, OFFS8 = 174760;

// lane mapping within a 32-lane group: r = g*8+s (g = gen, s = state)
// wq[j][i] (regs)   = P(child=s | parent=s^PX[i], pos j, gen g)      [lane (g,s)]
// emt_h[m*32+g*8+c] = P(obs m | state c, gen g)                      (fp16 LDS)
// etab_h[(m*4+j)*32+g*8+d] = sum_c P(c|d,j,g) em(m|c,g)              (fp16 LDS)

#define AG_ST(p, v) __hip_atomic_store((p), (v), __ATOMIC_RELAXED, __HIP_MEMORY_SCOPE_AGENT)
#define AG_LD(p) __hip_atomic_load((p), __ATOMIC_RELAXED, __HIP_MEMORY_SCOPE_AGENT)

template <int CTRL>
static __device__ __forceinline__ float dppmov(float v) {
  return __int_as_float(__builtin_amdgcn_update_dpp(0, __float_as_int(v), CTRL, 0xF, 0xF, true));
}
// octet sum, all 8 lanes, pure VALU
static __device__ __forceinline__ float bfly8(float v) {
  v += dppmov<0xB1>(v);   // s^1
  v += dppmov<0x4E>(v);   // s^2
  v += dppmov<0x141>(v);  // 7-s (row_half_mirror)
  return v;
}
constexpr int PX[8] = {0, 1, 2, 3, 7, 6, 5, 4};
struct O8 { float a[8]; };
static __device__ __forceinline__ O8 gather8(float v) {
  O8 o;
  o.a[0] = v;
  o.a[1] = dppmov<0xB1>(v);
  o.a[2] = dppmov<0x4E>(v);
  o.a[3] = dppmov<0x1B>(v);           // s^3
  o.a[4] = dppmov<0x141>(v);          // s^7
  o.a[5] = dppmov<0x141>(o.a[1]);     // s^6
  o.a[6] = dppmov<0x141>(o.a[2]);     // s^5
  o.a[7] = dppmov<0x141>(o.a[3]);     // s^4
  return o;
}
// top-down: child_prior[s] = sum_i wq[i] * prior[s^PX[i]]
static __device__ __forceinline__ float mvc(const float w[8], const O8& o) {
  float acc = 0.f;
#pragma unroll
  for (int i = 0; i < 8; i++) acc += w[i] * o.a[i];
  return acc;
}
static __device__ __forceinline__ float mv_sel(const float wq[4][8], const O8& o, int j) {
  float acc = 0.f;
#pragma unroll
  for (int i = 0; i < 8; i++) {
    float w01 = (j & 1) ? wq[1][i] : wq[0][i];
    float w23 = (j & 1) ? wq[3][i] : wq[2][i];
    float w = (j & 2) ? w23 : w01;
    acc += w * o.a[i];
  }
  return acc;
}
// upward: out[s] = sum_c P(child=c|parent=s,j) ratio[c] = sum_i DPP_{s^PX[i]}(wq[j][i]*ratio)
// (xor perms are self-inverse; cross-half mirror factored out of the 2nd quad-sum)
static __device__ __forceinline__ float mvup(const float w[8], float ratio) {
  float inA = w[0] * ratio;
  inA += dppmov<0xB1>(w[1] * ratio);
  inA += dppmov<0x4E>(w[2] * ratio);
  inA += dppmov<0x1B>(w[3] * ratio);
  float inB = w[4] * ratio;              // s^7 = 141
  inB += dppmov<0xB1>(w[5] * ratio);     // s^6 = 141*B1
  inB += dppmov<0x4E>(w[6] * ratio);     // s^5 = 141*4E
  inB += dppmov<0x1B>(w[7] * ratio);     // s^4 = 141*1B
  return inA + dppmov<0x141>(inB);
}
static __device__ __forceinline__ float rcpf(float x) { return __builtin_amdgcn_rcpf(x); }

// LDS (floats): [0,1024) wtd (phase0) -> rat5buf[16][32]/pri4buf[4][32] (phase1)
//               -> rat2buf[16][32]/rat1buf[4][32] (phase2)
// [1024,5120) emt_f32 (phase0, 3200 used) -> rat4h 8192 halves (phase2) -> reduce buf
// [5120,5920) emt_h 1600 halves | [5920,12320) etab_h 12800 halves
// total 49280 B -> 3 blocks/CU if VGPR alloc <= 168
__global__ __launch_bounds__(256, 2) void k_all(const int* __restrict__ x,
                                                const float* __restrict__ A,
                                                const float* __restrict__ Bm,
                                                const float* __restrict__ Pi,
                                                float* __restrict__ RAT4,
                                                float* __restrict__ blocksum,
                                                unsigned* __restrict__ ctr,
                                                float* __restrict__ out) {
  __shared__ __align__(16) float smem[12320];
  __shared__ float llb[4];
  __shared__ int lastf;
  float* wtd_l = smem;
  float* rat5buf = smem;            // phase 1 (wtd dead)
  float* pri4buf = smem + 512;
  float* rat2buf = smem;            // phase 2
  float* rat1buf = smem + 512;
  float* emt_f = smem + 1024;       // phase 0
  _Float16* rat4h = (_Float16*)(smem + 1024);  // phase 2
  _Float16* emt_h = (_Float16*)(smem + 5120);
  _Float16* etab_h = (_Float16*)(smem + 5920);

  int t = threadIdx.x, r = t & 31, g = r >> 3, s = r & 7, grp = t >> 5;
  int b = blockIdx.x, tree = b >> 6;  // 64 blocks/tree

  // ---------------- phase 0: tables ----------------
  if (t < 128) {  // A softmax over child state; thread owns column (d,j,gg)
    int d = t >> 4, j = (t >> 2) & 3, gg = t & 3;
    float v[8], sum = 0.f;
#pragma unroll
    for (int ss = 0; ss < 8; ss++) { v[ss] = __expf(A[((ss * 8 + d) * 4 + j) * 4 + gg]); sum += v[ss]; }
    float inv = rcpf(sum);
#pragma unroll
    for (int ss = 0; ss < 8; ss++) wtd_l[(j * 8 + d) * 32 + gg * 8 + ss] = v[ss] * inv;
  }
  if (t < 4) llb[t] = 0.f;
  {  // emission softmax over m: 32 rows (c,gg) x 8 octet partitions
    int row = t >> 3, part = t & 7, c = row >> 2, gg = row & 3;
    int m0 = part < 4 ? part * 13 : 52 + (part - 4) * 12;
    int mn = part < 4 ? 13 : 12;
    float sum = 0.f;
    for (int m = m0; m < m0 + mn; m++) sum += __expf(Bm[(c * 100 + m) * 4 + gg]);
    sum = bfly8(sum);
    float inv = rcpf(sum);
    for (int m = m0; m < m0 + mn; m++) {
      float e = __expf(Bm[(c * 100 + m) * 4 + gg]) * inv;
      emt_f[m * 32 + gg * 8 + c] = e;
      emt_h[m * 32 + gg * 8 + c] = (_Float16)e;
    }
  }
  float pit_r;  // per-lane root prior (no LDS)
  {
    float sum = 0.f, own = 0.f;
#pragma unroll
    for (int c = 0; c < 8; c++) {
      float e = __expf(Pi[c * 4 + g]);
      sum += e;
      if (c == s) own = e;
    }
    pit_r = own * rcpf(sum);
  }
  __syncthreads();
  float wq[4][8];
#pragma unroll
  for (int j = 0; j < 4; j++)
#pragma unroll
    for (int i = 0; i < 8; i++) wq[j][i] = wtd_l[(j * 8 + (s ^ PX[i])) * 32 + r];
  {  // Etab: group handles j = grp&3, m-half = grp>>2 (uses upward matvec on em rows)
    int j = grp & 3, half = grp >> 2;
    float wsel[8];
#pragma unroll
    for (int i = 0; i < 8; i++) {
      float w01 = (j & 1) ? wq[1][i] : wq[0][i];
      float w23 = (j & 1) ? wq[3][i] : wq[2][i];
      wsel[i] = (j & 2) ? w23 : w01;
    }
    for (int m = half * 50; m < half * 50 + 50; m++)
      etab_h[(m * 4 + j) * 32 + r] = (_Float16)mvup(wsel, emt_f[m * 32 + r]);
  }
  __syncthreads();  // wtd/emt_f dead; rat5buf live

  // ---------------- phase 1: two level-5 subtrees per group ----------------
  float acc = 0.f;
#pragma unroll 1
  for (int round = 0; round < 2; round++) {
    int n5 = b * 16 + round * 8 + grp;
    float v = pit_r, pri4 = 0.f;
#pragma unroll
    for (int k = 1; k <= 5; k++) {
      O8 o = gather8(v);
      int j = (n5 >> (2 * (5 - k))) & 3;
      v = mv_sel(wq, o, j);
      if (k == 4) pri4 = v;
    }
    float v5 = v;
    O8 o5 = gather8(v5);

    const int4* x8v = (const int4*)(x + OFFS8 + n5 * 64);
    const int4* x7v = (const int4*)(x + OFFS7 + n5 * 16);
    int4 x6v = *(const int4*)(x + OFFS6 + n5 * 4);
    int x5s = x[OFFS5 + n5];
    const int* x6a = (const int*)&x6v;

    float l6r[4];
#pragma unroll
    for (int q6 = 0; q6 < 4; q6++) {
      int4 x7 = x7v[q6];
      const int* x7a = (const int*)&x7;
      float u6 = mvc(wq[q6], o5);
      O8 o6 = gather8(u6);
      float Ep[4][4];
#pragma unroll
      for (int q7 = 0; q7 < 4; q7++) {
        int4 xl = x8v[q6 * 4 + q7];
        const int* xla = (const int*)&xl;
#pragma unroll
        for (int j = 0; j < 4; j++) Ep[q7][j] = (float)etab_h[(xla[j] * 4 + j) * 32 + r];
      }
      float rat7[4];
#pragma unroll
      for (int q7 = 0; q7 < 4; q7++) {
        float u7 = mvc(wq[q7], o6);
        float n0 = bfly8(u7 * Ep[q7][0]);
        float n1 = bfly8(u7 * Ep[q7][1]);
        float n2 = bfly8(u7 * Ep[q7][2]);
        float n3 = bfly8(u7 * Ep[q7][3]);
        float p01 = n0 * n1, p23 = n2 * n3;
        float prodL = (Ep[q7][0] * Ep[q7][1] * rcpf(p01)) * (Ep[q7][2] * Ep[q7][3] * rcpf(p23));
        float em = (float)emt_h[x7a[q7] * 32 + r];
        float nu7 = bfly8(u7 * em * prodL);
        acc += __logf(p01 * p23) + __logf(nu7);
        rat7[q7] = em * prodL * rcpf(nu7);
      }
      float prod6 = mvup(wq[0], rat7[0]) * mvup(wq[1], rat7[1]) *
                    mvup(wq[2], rat7[2]) * mvup(wq[3], rat7[3]);
      float em6 = (float)emt_h[x6a[q6] * 32 + r];
      float nu6 = bfly8(u6 * em6 * prod6);
      acc += __logf(nu6);
      l6r[q6] = em6 * prod6 * rcpf(nu6);
    }
    float prod5 = mvup(wq[0], l6r[0]) * mvup(wq[1], l6r[1]) *
                  mvup(wq[2], l6r[2]) * mvup(wq[3], l6r[3]);
    float em5 = (float)emt_h[x5s * 32 + r];
    float nu5 = bfly8(v5 * em5 * prod5);
    acc += __logf(nu5);
    rat5buf[(round * 8 + grp) * 32 + r] = em5 * prod5 * rcpf(nu5);
    if ((grp & 3) == 0) pri4buf[(round * 2 + (grp >> 2)) * 32 + r] = pri4;
  }
  __syncthreads();

  // level-4: 4 nodes/block
  if (grp < 4) {
    int n4 = b * 4 + grp;
    float prod = mvup(wq[0], rat5buf[(grp * 4 + 0) * 32 + r]) *
                 mvup(wq[1], rat5buf[(grp * 4 + 1) * 32 + r]) *
                 mvup(wq[2], rat5buf[(grp * 4 + 2) * 32 + r]) *
                 mvup(wq[3], rat5buf[(grp * 4 + 3) * 32 + r]);
    float em = (float)emt_h[x[OFFS4 + n4] * 32 + r];
    float nu = bfly8(pri4buf[grp * 32 + r] * em * prod);
    acc += __logf(nu);
    AG_ST(&RAT4[n4 * 32 + r], em * prod * rcpf(nu));
  }

  if (s == 0) atomicAdd(&llb[g], acc);
  __syncthreads();
  if (t < 4) AG_ST(&blocksum[b * 4 + t], llb[t]);
  asm volatile("s_waitcnt vmcnt(0)" ::: "memory");
  __syncthreads();
  if (t == 0) {
    unsigned old = __hip_atomic_fetch_add(&ctr[tree * 32], 1u, __ATOMIC_RELAXED,
                                          __HIP_MEMORY_SCOPE_AGENT);
    lastf = (old == 63u || old == 0xAAAAAAE9u) ? 1 : 0;  // zero-init or 0xAA poison
  }
  __syncthreads();
  if (!lastf) return;

  // ---------------- phase 2: last block of the tree, levels 3..0 ----------------
  {  // stage tree's RAT4 (8192 f) -> fp16 LDS, batched agent loads
    float tmp[8];
#pragma unroll
    for (int ib = 0; ib < 4; ib++) {
#pragma unroll
      for (int i = 0; i < 8; i++) tmp[i] = AG_LD(&RAT4[tree * 8192 + (ib * 8 + i) * 256 + t]);
#pragma unroll
      for (int i = 0; i < 8; i++) rat4h[(ib * 8 + i) * 256 + t] = (_Float16)tmp[i];
    }
  }
  if (t < 4) llb[t] = 0.f;
  __syncthreads();

  float acc2 = 0.f;
#pragma unroll 1
  for (int ii = 0; ii < 2; ii++) {
    int l2 = ii * 8 + grp;
    int n2g = tree * 16 + l2;
    float v2 = pit_r;
#pragma unroll
    for (int k = 1; k <= 2; k++) {
      O8 o = gather8(v2);
      int j = (n2g >> (2 * (2 - k))) & 3;
      v2 = mv_sel(wq, o, j);
    }
    O8 o2 = gather8(v2);
    float rat3[4];
#pragma unroll
    for (int j3 = 0; j3 < 4; j3++) {
      int i3l = l2 * 4 + j3;
      float p3 = mvc(wq[j3], o2);
      float prod = mvup(wq[0], (float)rat4h[(i3l * 4 + 0) * 32 + r]) *
                   mvup(wq[1], (float)rat4h[(i3l * 4 + 1) * 32 + r]) *
                   mvup(wq[2], (float)rat4h[(i3l * 4 + 2) * 32 + r]) *
                   mvup(wq[3], (float)rat4h[(i3l * 4 + 3) * 32 + r]);
      float em = (float)emt_h[x[OFFS3 + tree * 64 + i3l] * 32 + r];
      float nu = bfly8(p3 * em * prod);
      acc2 += __logf(nu);
      rat3[j3] = em * prod * rcpf(nu);
    }
    float prod2 = mvup(wq[0], rat3[0]) * mvup(wq[1], rat3[1]) *
                  mvup(wq[2], rat3[2]) * mvup(wq[3], rat3[3]);
    float em2 = (float)emt_h[x[OFFS2 + n2g] * 32 + r];
    float nu2 = bfly8(v2 * em2 * prod2);
    acc2 += __logf(nu2);
    rat2buf[l2 * 32 + r] = em2 * prod2 * rcpf(nu2);
  }
  __syncthreads();
  if (grp < 4) {  // level 1
    float v1 = mv_sel(wq, gather8(pit_r), grp);
    float prod = mvup(wq[0], rat2buf[(grp * 4 + 0) * 32 + r]) *
                 mvup(wq[1], rat2buf[(grp * 4 + 1) * 32 + r]) *
                 mvup(wq[2], rat2buf[(grp * 4 + 2) * 32 + r]) *
                 mvup(wq[3], rat2buf[(grp * 4 + 3) * 32 + r]);
    float em = (float)emt_h[x[OFFS1 + tree * 4 + grp] * 32 + r];
    float nu = bfly8(v1 * em * prod);
    acc2 += __logf(nu);
    rat1buf[grp * 32 + r] = em * prod * rcpf(nu);
  }
  __syncthreads();
  if (grp == 0) {  // root
    float prod = mvup(wq[0], rat1buf[0 * 32 + r]) * mvup(wq[1], rat1buf[1 * 32 + r]) *
                 mvup(wq[2], rat1buf[2 * 32 + r]) * mvup(wq[3], rat1buf[3 * 32 + r]);
    float em = (float)emt_h[x[tree] * 32 + r];
    float nu = bfly8(pit_r * em * prod);
    acc2 += __logf(nu);
  }
  if (s == 0) atomicAdd(&llb[g], acc2);
  __syncthreads();
  // reduce 64 blocks x 4 gens (gen preserved mod 4)
  float* red = smem + 1024;
  red[t] = AG_LD(&blocksum[tree * 256 + t]);
  __syncthreads();
#pragma unroll
  for (int off = 128; off >= 4; off >>= 1) {
    if (t < off) red[t] += red[t + off];
    __syncthreads();
  }
  if (t < 4) out[tree * 4 + t] = red[t] + llb[t];
}

extern "C" void kernel_launch(void* const* d_in, const int* in_sizes, int n_in,
                              void* d_out, int out_size, void* d_ws, size_t ws_size,
                              hipStream_t stream) {
  const int* x = (const int*)d_in[0];
  const float* A = (const float*)d_in[1];
  const float* Bm = (const float*)d_in[2];
  const float* Pi = (const float*)d_in[3];
  float* ws = (float*)d_ws;
  unsigned* ctr = (unsigned*)d_ws;  // 8 trees x stride-32 uints (poison-based count)
  float* blocksum = ws + 256;       // 512 blocks x 4
  float* RAT4 = ws + 256 + 2048;    // 2048*32
  float* out = (float*)d_out;

  k_all<<<512, 256, 0, stream>>>(x, A, Bm, Pi, RAT4, blocksum, ctr, out);
}